// Round 1
// baseline (35.475 us; speedup 1.0000x reference)
//
#include <hip/hip_runtime.h>

#define NQ 14
#define SIZE 16384  // 2^14 floats = 64 KiB LDS

// ---- in-register gates on 64-amplitude local tile (all indices compile-time) ----
template<int B>
__device__ __forceinline__ void ry_g(float (&v)[64], float c, float s) {
#pragma unroll
  for (int k = 0; k < 64; ++k)
    if (!(k & (1 << B))) {
      float a0 = v[k], a1 = v[k | (1 << B)];
      v[k]            = c * a0 - s * a1;
      v[k | (1 << B)] = s * a0 + c * a1;
    }
}

template<int CB, int TB>
__device__ __forceinline__ void cnot_g(float (&v)[64]) {
#pragma unroll
  for (int k = 0; k < 64; ++k)
    if ((k & (1 << CB)) && !(k & (1 << TB))) {
      float tmp        = v[k];
      v[k]             = v[k | (1 << TB)];
      v[k | (1 << TB)] = tmp;
    }
}

// Physical LDS layout: amp[i] stored at float index  i ^ ((i>>6)&31)  (bank-conflict-free
// for all three access configs below; byte offsets decompose as thread_base ^ K(k)).
__device__ __forceinline__ constexpr int KA(int k) { return (k << 10) ^ ((k & 7) << 4); }
__device__ __forceinline__ constexpr int KB(int k) { return (k << 5) ^ ((k >> 3) << 2); }
__device__ __forceinline__ constexpr int KC(int k) { return k << 2; }

// Config A: local wires 0..5  (i = k<<8 | t)      wire q <-> k-bit (5-q)
// Config B: local wires 5..10 (i = hi<<9|k<<3|lo) wire q <-> k-bit (10-q), hi=t>>3, lo=t&7
// Config C: local wires 8..13 (i = t<<6 | k)      wire q <-> k-bit (13-q)

__global__ __launch_bounds__(256) void vqc_kernel(const float* __restrict__ x,
                                                  const float* __restrict__ p,
                                                  float* __restrict__ out) {
  __shared__ float lds[SIZE];
  char* ldsb  = reinterpret_cast<char*>(lds);
  const int t = threadIdx.x;
  const int b = blockIdx.x;

  const int hi = t >> 3, lo = t & 7;
  const int uA = (t ^ (t >> 6)) << 2;
  const int uB = (hi << 11) ^ (lo << 2) ^ ((hi & 3) << 5);
  const int uC = (t << 8) ^ ((t & 31) << 2);

  float loc[64];

  // ================= layer 0 =================
  // Encoding RY(x) and layer-0 RY(p) compose: product state with angles x+p, then CNOTs.
  {
    float cw[NQ], sw[NQ];
#pragma unroll
    for (int q = 0; q < NQ; ++q) {
      float th = 0.5f * (x[b * NQ + q] + p[q]);
      __sincosf(th, &sw[q], &cw[q]);
    }
    // wires 6..13 live in thread bits (bit 13-q of t)
    float P = 1.0f;
#pragma unroll
    for (int q = 6; q < NQ; ++q)
      P *= ((t >> (13 - q)) & 1) ? sw[q] : cw[q];
    // wires 0..5 in local bits (k-bit 5-q)
    loc[0] = P;
#pragma unroll
    for (int bb = 0; bb < 6; ++bb) {
      const int q = 5 - bb;
#pragma unroll
      for (int m = 0; m < 64; ++m)
        if (m < (1 << bb)) {
          loc[m | (1 << bb)] = loc[m] * sw[q];
          loc[m]             = loc[m] * cw[q];
        }
    }
    // layer-0 CNOTs local to A: (0,1)(2,3)(4,5) then (1,2)(3,4)
    cnot_g<5, 4>(loc); cnot_g<3, 2>(loc); cnot_g<1, 0>(loc);
    cnot_g<4, 3>(loc); cnot_g<2, 1>(loc);
#pragma unroll
    for (int k = 0; k < 64; ++k)
      *reinterpret_cast<float*>(ldsb + (uA ^ KA(k))) = loc[k];
    __syncthreads();

    // pass B: CNOTs (6,7)(8,9) then (5,6)(7,8)
#pragma unroll
    for (int k = 0; k < 64; ++k)
      loc[k] = *reinterpret_cast<float*>(ldsb + (uB ^ KB(k)));
    cnot_g<4, 3>(loc); cnot_g<2, 1>(loc);
    cnot_g<5, 4>(loc); cnot_g<3, 2>(loc);
#pragma unroll
    for (int k = 0; k < 64; ++k)
      *reinterpret_cast<float*>(ldsb + (uB ^ KB(k))) = loc[k];
    __syncthreads();

    // pass C: CNOTs (10,11)(12,13) then (9,10)(11,12)
#pragma unroll
    for (int k = 0; k < 64; ++k)
      loc[k] = *reinterpret_cast<float*>(ldsb + (uC ^ KC(k)));
    cnot_g<3, 2>(loc); cnot_g<1, 0>(loc);
    cnot_g<4, 3>(loc); cnot_g<2, 1>(loc);
#pragma unroll
    for (int k = 0; k < 64; ++k)
      *reinterpret_cast<float*>(ldsb + (uC ^ KC(k))) = loc[k];
    __syncthreads();
  }

  // ================= layers 1..5 =================
  for (int l = 1; l < 6; ++l) {
    const float* pp = p + l * NQ;
    float c, s;

    // ---- pass A: RY 0..5, CNOT (0,1)(2,3)(4,5) then (1,2)(3,4) ----
#pragma unroll
    for (int k = 0; k < 64; ++k)
      loc[k] = *reinterpret_cast<float*>(ldsb + (uA ^ KA(k)));
    __sincosf(0.5f * pp[0], &s, &c); ry_g<5>(loc, c, s);
    __sincosf(0.5f * pp[1], &s, &c); ry_g<4>(loc, c, s);
    __sincosf(0.5f * pp[2], &s, &c); ry_g<3>(loc, c, s);
    __sincosf(0.5f * pp[3], &s, &c); ry_g<2>(loc, c, s);
    __sincosf(0.5f * pp[4], &s, &c); ry_g<1>(loc, c, s);
    __sincosf(0.5f * pp[5], &s, &c); ry_g<0>(loc, c, s);
    cnot_g<5, 4>(loc); cnot_g<3, 2>(loc); cnot_g<1, 0>(loc);
    cnot_g<4, 3>(loc); cnot_g<2, 1>(loc);
#pragma unroll
    for (int k = 0; k < 64; ++k)
      *reinterpret_cast<float*>(ldsb + (uA ^ KA(k))) = loc[k];
    __syncthreads();

    // ---- pass B: RY 6..10, CNOT (6,7)(8,9) then (5,6)(7,8) ----
#pragma unroll
    for (int k = 0; k < 64; ++k)
      loc[k] = *reinterpret_cast<float*>(ldsb + (uB ^ KB(k)));
    __sincosf(0.5f * pp[6], &s, &c);  ry_g<4>(loc, c, s);
    __sincosf(0.5f * pp[7], &s, &c);  ry_g<3>(loc, c, s);
    __sincosf(0.5f * pp[8], &s, &c);  ry_g<2>(loc, c, s);
    __sincosf(0.5f * pp[9], &s, &c);  ry_g<1>(loc, c, s);
    __sincosf(0.5f * pp[10], &s, &c); ry_g<0>(loc, c, s);
    cnot_g<4, 3>(loc); cnot_g<2, 1>(loc);
    cnot_g<5, 4>(loc); cnot_g<3, 2>(loc);
#pragma unroll
    for (int k = 0; k < 64; ++k)
      *reinterpret_cast<float*>(ldsb + (uB ^ KB(k))) = loc[k];
    __syncthreads();

    // ---- pass C: RY 11..13, CNOT (10,11)(12,13) then (9,10)(11,12) ----
#pragma unroll
    for (int k = 0; k < 64; ++k)
      loc[k] = *reinterpret_cast<float*>(ldsb + (uC ^ KC(k)));
    __sincosf(0.5f * pp[11], &s, &c); ry_g<2>(loc, c, s);
    __sincosf(0.5f * pp[12], &s, &c); ry_g<1>(loc, c, s);
    __sincosf(0.5f * pp[13], &s, &c); ry_g<0>(loc, c, s);
    cnot_g<3, 2>(loc); cnot_g<1, 0>(loc);
    cnot_g<4, 3>(loc); cnot_g<2, 1>(loc);
    if (l < 5) {
#pragma unroll
      for (int k = 0; k < 64; ++k)
        *reinterpret_cast<float*>(ldsb + (uC ^ KC(k))) = loc[k];
      __syncthreads();
    }
  }

  // ================= output: <Z0> = sum(amp^2 * (1-2*bit13)) =================
  // Config C: i = t*64 + k  ->  bit13(i) = bit7(t)
  float acc = 0.f;
#pragma unroll
  for (int k = 0; k < 64; ++k) acc += loc[k] * loc[k];
  if (t & 128) acc = -acc;
#pragma unroll
  for (int off = 32; off > 0; off >>= 1)
    acc += __shfl_down(acc, off, 64);
  __syncthreads();  // all LDS state reads are done; safe to reuse for reduction
  if ((t & 63) == 0) lds[t >> 6] = acc;
  __syncthreads();
  if (t == 0) out[b] = lds[0] + lds[1] + lds[2] + lds[3];
}

extern "C" void kernel_launch(void* const* d_in, const int* in_sizes, int n_in,
                              void* d_out, int out_size, void* d_ws, size_t ws_size,
                              hipStream_t stream) {
  const float* x   = (const float*)d_in[0];   // (BATCH, 14) float32
  const float* prm = (const float*)d_in[1];   // (84,)      float32
  float* out       = (float*)d_out;           // (BATCH,)   float32
  const int batch  = in_sizes[0] / NQ;        // 128
  if (batch <= 0) return;
  vqc_kernel<<<dim3(batch), dim3(256), 0, stream>>>(x, prm, out);
}

// Round 2
// 29.454 us; speedup vs baseline: 1.2044x; 1.2044x over previous
//
#include <hip/hip_runtime.h>

#define NQ 14
#define SIZE 16384  // 2^14 floats = 64 KiB LDS

typedef float f2 __attribute__((ext_vector_type(2)));

// ---- packed gates on 32 x float2 local tile (indices compile-time) ----
// vec bit B pairs float2's; elementwise ops compile to v_pk_mul/v_pk_fma_f32.
template<int B>
__device__ __forceinline__ void ry_v(f2 (&v)[32], float c, float s) {
  const f2 cc = {c, c}, ss = {s, s};
#pragma unroll
  for (int j = 0; j < 32; ++j)
    if (!(j & (1 << B))) {
      f2 a = v[j], b = v[j | (1 << B)];
      v[j]            = a * cc - b * ss;   // contracts to pk_mul + pk_fma
      v[j | (1 << B)] = a * ss + b * cc;
    }
}

// RY on the intra-pair bit (element lane of the float2)
__device__ __forceinline__ void ry_intra(f2 (&v)[32], float c, float s) {
  const f2 cc = {c, c}, ms = {-s, s};
#pragma unroll
  for (int j = 0; j < 32; ++j) {
    f2 sw = __builtin_shufflevector(v[j], v[j], 1, 0);  // (a1, a0)
    v[j]  = v[j] * cc + sw * ms;  // (c*a0 - s*a1, c*a1 + s*a0)
  }
}

template<int CB, int TB>
__device__ __forceinline__ void cnot_v(f2 (&v)[32]) {
#pragma unroll
  for (int j = 0; j < 32; ++j)
    if ((j & (1 << CB)) && !(j & (1 << TB))) {
      f2 tmp           = v[j];
      v[j]             = v[j | (1 << TB)];
      v[j | (1 << TB)] = tmp;
    }
}

// CNOT: control = vec bit CB, target = intra-pair bit (swap elements)
template<int CB>
__device__ __forceinline__ void cnot_ci(f2 (&v)[32]) {
#pragma unroll
  for (int j = 0; j < 32; ++j)
    if (j & (1 << CB)) v[j] = __builtin_shufflevector(v[j], v[j], 1, 0);
}

// Physical LDS layout: amp[i] at float index i ^ ((i>>6)&31) (conflict-free, verified R1).
__device__ __forceinline__ constexpr int KA(int k) { return (k << 10) ^ ((k & 7) << 4); }
__device__ __forceinline__ constexpr int KB(int k) { return (k << 5) ^ ((k >> 3) << 2); }
__device__ __forceinline__ constexpr int KC(int k) { return k << 2; }

// Config A: local wires 0..5  (i = k<<8 | t)      wire q <-> k-bit (5-q);  pair bit = wire 5
// Config B: local wires 5..10 (i = hi<<9|k<<3|lo) wire q <-> k-bit (10-q); pair bit = wire 10
// Config C: local wires 8..13 (i = t<<6 | k)      wire q <-> k-bit (13-q); pair bit = wire 13
// vec bit = k-bit - 1.

__global__ __launch_bounds__(256) void vqc_kernel(const float* __restrict__ x,
                                                  const float* __restrict__ p,
                                                  float* __restrict__ out) {
  __shared__ float lds[SIZE];
  char* ldsb  = reinterpret_cast<char*>(lds);
  const int t = threadIdx.x;
  const int b = blockIdx.x;

  const int hi = t >> 3, lo = t & 7;
  const int uA = (t ^ (t >> 6)) << 2;
  const int uB = (hi << 11) ^ (lo << 2) ^ ((hi & 3) << 5);
  const int uC = (t << 8) ^ ((t & 31) << 2);

  f2 loc[32];

#define LDS_RD(U, KF)                                                        \
  _Pragma("unroll") for (int j = 0; j < 32; ++j) {                           \
    loc[j].x = *reinterpret_cast<float*>(ldsb + ((U) ^ KF(2 * j)));          \
    loc[j].y = *reinterpret_cast<float*>(ldsb + ((U) ^ KF(2 * j + 1)));      \
  }
#define LDS_WR(U, KF)                                                        \
  _Pragma("unroll") for (int j = 0; j < 32; ++j) {                           \
    *reinterpret_cast<float*>(ldsb + ((U) ^ KF(2 * j)))     = loc[j].x;      \
    *reinterpret_cast<float*>(ldsb + ((U) ^ KF(2 * j + 1))) = loc[j].y;      \
  }

  // ================= layer 0 =================
  // Encoding RY(x) and layer-0 RY(p) compose into one product state, then CNOTs.
  {
    float cw[NQ], sw[NQ];
#pragma unroll
    for (int q = 0; q < NQ; ++q) {
      float th = 0.5f * (x[b * NQ + q] + p[q]);
      sw[q] = __sinf(th);
      cw[q] = __cosf(th);
    }
    // wires 6..13 live in thread bits (bit 13-q of t)
    float P = 1.0f;
#pragma unroll
    for (int q = 6; q < NQ; ++q)
      P *= ((t >> (13 - q)) & 1) ? sw[q] : cw[q];
    // wire 5 = element lane; wires 0..4 = vec bits 4..0
    loc[0] = (f2){P * cw[5], P * sw[5]};
#pragma unroll
    for (int vb = 0; vb < 5; ++vb) {
      const int q = 4 - vb;
      const f2 cq = {cw[q], cw[q]}, sq = {sw[q], sw[q]};
#pragma unroll
      for (int m = 0; m < 32; ++m)
        if (m < (1 << vb)) {
          loc[m | (1 << vb)] = loc[m] * sq;
          loc[m]             = loc[m] * cq;
        }
    }
    // layer-0 CNOTs in A: even (0,1)(2,3)(4,5) then odd (1,2)(3,4)
    cnot_v<4, 3>(loc); cnot_v<2, 1>(loc); cnot_ci<0>(loc);
    cnot_v<3, 2>(loc); cnot_v<1, 0>(loc);
    LDS_WR(uA, KA)
    __syncthreads();

    // pass B: even (6,7)(8,9) then odd (5,6)(7,8)
    LDS_RD(uB, KB)
    cnot_v<3, 2>(loc); cnot_v<1, 0>(loc);
    cnot_v<4, 3>(loc); cnot_v<2, 1>(loc);
    LDS_WR(uB, KB)
    __syncthreads();

    // pass C: even (10,11)(12,13) then odd (9,10)(11,12)
    LDS_RD(uC, KC)
    cnot_v<2, 1>(loc); cnot_ci<0>(loc);
    cnot_v<3, 2>(loc); cnot_v<1, 0>(loc);
    LDS_WR(uC, KC)
    __syncthreads();
  }

  // ================= layers 1..5 =================
  for (int l = 1; l < 6; ++l) {
    const float* pp = p + l * NQ;
    float c, s, th;

    // ---- pass A: RY 0..5, even (0,1)(2,3)(4,5), odd (1,2)(3,4) ----
    LDS_RD(uA, KA)
    th = 0.5f * pp[0]; s = __sinf(th); c = __cosf(th); ry_v<4>(loc, c, s);
    th = 0.5f * pp[1]; s = __sinf(th); c = __cosf(th); ry_v<3>(loc, c, s);
    th = 0.5f * pp[2]; s = __sinf(th); c = __cosf(th); ry_v<2>(loc, c, s);
    th = 0.5f * pp[3]; s = __sinf(th); c = __cosf(th); ry_v<1>(loc, c, s);
    th = 0.5f * pp[4]; s = __sinf(th); c = __cosf(th); ry_v<0>(loc, c, s);
    th = 0.5f * pp[5]; s = __sinf(th); c = __cosf(th); ry_intra(loc, c, s);
    cnot_v<4, 3>(loc); cnot_v<2, 1>(loc); cnot_ci<0>(loc);
    cnot_v<3, 2>(loc); cnot_v<1, 0>(loc);
    LDS_WR(uA, KA)
    __syncthreads();

    // ---- pass B: RY 6..10, even (6,7)(8,9), odd (5,6)(7,8) ----
    LDS_RD(uB, KB)
    th = 0.5f * pp[6];  s = __sinf(th); c = __cosf(th); ry_v<3>(loc, c, s);
    th = 0.5f * pp[7];  s = __sinf(th); c = __cosf(th); ry_v<2>(loc, c, s);
    th = 0.5f * pp[8];  s = __sinf(th); c = __cosf(th); ry_v<1>(loc, c, s);
    th = 0.5f * pp[9];  s = __sinf(th); c = __cosf(th); ry_v<0>(loc, c, s);
    th = 0.5f * pp[10]; s = __sinf(th); c = __cosf(th); ry_intra(loc, c, s);
    cnot_v<3, 2>(loc); cnot_v<1, 0>(loc);
    cnot_v<4, 3>(loc); cnot_v<2, 1>(loc);
    LDS_WR(uB, KB)
    __syncthreads();

    // ---- pass C: RY 11..13, even (10,11)(12,13), odd (9,10)(11,12) ----
    LDS_RD(uC, KC)
    th = 0.5f * pp[11]; s = __sinf(th); c = __cosf(th); ry_v<1>(loc, c, s);
    th = 0.5f * pp[12]; s = __sinf(th); c = __cosf(th); ry_v<0>(loc, c, s);
    th = 0.5f * pp[13]; s = __sinf(th); c = __cosf(th); ry_intra(loc, c, s);
    cnot_v<2, 1>(loc); cnot_ci<0>(loc);
    cnot_v<3, 2>(loc); cnot_v<1, 0>(loc);
    if (l < 5) {
      LDS_WR(uC, KC)
      __syncthreads();
    }
  }

  // ================= output: <Z0> = sum(amp^2 * (1-2*bit13)) =================
  // Config C: i = t*64 + k -> bit13(i) = bit7(t)
  float acc = 0.f;
#pragma unroll
  for (int j = 0; j < 32; ++j) acc += loc[j].x * loc[j].x + loc[j].y * loc[j].y;
  if (t & 128) acc = -acc;
#pragma unroll
  for (int off = 32; off > 0; off >>= 1)
    acc += __shfl_down(acc, off, 64);
  __syncthreads();  // all LDS state reads done; reuse for reduction
  if ((t & 63) == 0) lds[t >> 6] = acc;
  __syncthreads();
  if (t == 0) out[b] = lds[0] + lds[1] + lds[2] + lds[3];
}

extern "C" void kernel_launch(void* const* d_in, const int* in_sizes, int n_in,
                              void* d_out, int out_size, void* d_ws, size_t ws_size,
                              hipStream_t stream) {
  const float* x   = (const float*)d_in[0];   // (BATCH, 14) float32
  const float* prm = (const float*)d_in[1];   // (84,)      float32
  float* out       = (float*)d_out;           // (BATCH,)   float32
  const int batch  = in_sizes[0] / NQ;        // 128
  if (batch <= 0) return;
  vqc_kernel<<<dim3(batch), dim3(256), 0, stream>>>(x, prm, out);
}

// Round 3
// 26.422 us; speedup vs baseline: 1.3427x; 1.1148x over previous
//
#include <hip/hip_runtime.h>

#define NQ 14

typedef float f2 __attribute__((ext_vector_type(2)));
typedef float f4 __attribute__((ext_vector_type(4)));

// ======== in-register gates on 32 x f2 tile (vec bits 0..4 = reg index, elem = f2 lane) ========
template<int B>
__device__ __forceinline__ void ry_v(f2 (&v)[32], float c, float s) {
  const f2 cc = {c, c}, ss = {s, s};
#pragma unroll
  for (int j = 0; j < 32; ++j)
    if (!(j & (1 << B))) {
      f2 a = v[j], b = v[j | (1 << B)];
      v[j]            = a * cc - b * ss;
      v[j | (1 << B)] = a * ss + b * cc;
    }
}

__device__ __forceinline__ void ry_intra(f2 (&v)[32], float c, float s) {
  const f2 cc = {c, c}, ms = {-s, s};
#pragma unroll
  for (int j = 0; j < 32; ++j) {
    f2 sw = __builtin_shufflevector(v[j], v[j], 1, 0);
    v[j]  = v[j] * cc + sw * ms;
  }
}

template<int CB, int TB>
__device__ __forceinline__ void cnot_v(f2 (&v)[32]) {
#pragma unroll
  for (int j = 0; j < 32; ++j)
    if ((j & (1 << CB)) && !(j & (1 << TB))) {
      f2 tmp = v[j]; v[j] = v[j | (1 << TB)]; v[j | (1 << TB)] = tmp;
    }
}

template<int CB>  // control = vec bit CB, target = elem bit
__device__ __forceinline__ void cnot_ci(f2 (&v)[32]) {
#pragma unroll
  for (int j = 0; j < 32; ++j)
    if (j & (1 << CB)) v[j] = __builtin_shufflevector(v[j], v[j], 1, 0);
}

template<int TB>  // control = elem bit, target = vec bit TB
__device__ __forceinline__ void cnot_ic(f2 (&v)[32]) {
#pragma unroll
  for (int j = 0; j < 32; ++j)
    if (!(j & (1 << TB))) {
      float tmp = v[j].y; v[j].y = v[j | (1 << TB)].y; v[j | (1 << TB)].y = tmp;
    }
}

// ======== LDS transfer: 16 x ds_read/write_b128, offsets are compile-time immediates ========
template<int STRIDE>
__device__ __forceinline__ void read_lin(f2 (&loc)[32], const char* ldsb, int base) {
#pragma unroll
  for (int r = 0; r < 16; ++r) {
    f4 v = *reinterpret_cast<const f4*>(ldsb + base + STRIDE * r);
    loc[2 * r]     = (f2){v.x, v.y};
    loc[2 * r + 1] = (f2){v.z, v.w};
  }
}
template<int STRIDE>
__device__ __forceinline__ void write_lin(const f2 (&loc)[32], char* ldsb, int base) {
#pragma unroll
  for (int r = 0; r < 16; ++r) {
    f4 v = {loc[2 * r].x, loc[2 * r].y, loc[2 * r + 1].x, loc[2 * r + 1].y};
    *reinterpret_cast<f4*>(ldsb + base + STRIDE * r) = v;
  }
}
// B'2 read of L_BC: quad index bits (r0,r1,r2,r3) -> byte mults (8192,16384,2048,4096)
__device__ __forceinline__ void read_b2(f2 (&loc)[32], const char* ldsb, int base) {
#pragma unroll
  for (int r = 0; r < 16; ++r) {
    const int off = 8192 * (r & 1) + 16384 * ((r >> 1) & 1) + 2048 * ((r >> 2) & 1) + 4096 * ((r >> 3) & 1);
    f4 v = *reinterpret_cast<const f4*>(ldsb + base + off);
    loc[2 * r]     = (f2){v.x, v.y};
    loc[2 * r + 1] = (f2){v.z, v.w};
  }
}
// B' gather-write: instr w = (k0,k1,k4,k5); block varies (k2,k3); j = k1+2k2+4k3+8k4+16k5, elem = k0
template<int M0, int M1, int M4, int M5>
__device__ __forceinline__ void write_gather(const f2 (&loc)[32], char* ldsb, int base) {
#pragma unroll
  for (int w = 0; w < 16; ++w) {
    const int k0 = w & 1, k1 = (w >> 1) & 1, k4 = (w >> 2) & 1, k5 = (w >> 3) & 1;
    const int jb = k1 + 8 * k4 + 16 * k5;
    f4 v = { k0 ? loc[jb].y     : loc[jb].x,
             k0 ? loc[jb + 2].y : loc[jb + 2].x,
             k0 ? loc[jb + 4].y : loc[jb + 4].x,
             k0 ? loc[jb + 6].y : loc[jb + 6].x };
    *reinterpret_cast<f4*>(ldsb + base + (M0 * k0 + M1 * k1 + M4 * k4 + M5 * k5)) = v;
  }
}

__device__ __forceinline__ void sc(float ang, float& s, float& c) {
  float th = 0.5f * ang; s = __sinf(th); c = __cosf(th);
}

// ======== pass gate bodies (bit positions derived per-pass; see layout derivation) ========
// A numbering: i8=elem, i9=v0, i10=v1, i11=v2, i12=v3, i13=v4  (bit b <-> wire 13-b)
// C numbering: i4=elem, i5=v0, i0=v1, i1=v2, i2=v3, i3=v4
// B'1 numbering: i8=elem, i9=v0, i4=v1, i5=v2, i6=v3, i7=v4
// B'2 numbering: i4=elem, i5=v0, i8=v1, i9=v2, i6=v3, i7=v4

__device__ __forceinline__ void gates_B1(f2 (&loc)[32], const float* pp, bool withRY) {
  float s, c;
  if (withRY) {  // RY wires 6..9 = bits 7..4
    sc(pp[6], s, c); ry_v<4>(loc, c, s);
    sc(pp[7], s, c); ry_v<3>(loc, c, s);
    sc(pp[8], s, c); ry_v<2>(loc, c, s);
    sc(pp[9], s, c); ry_v<1>(loc, c, s);
  }
  cnot_v<4, 3>(loc);  // E(7,6)
  cnot_v<2, 1>(loc);  // E(5,4)
  cnot_ic<4>(loc);    // O(8,7)
  cnot_v<3, 2>(loc);  // O(6,5)
}

__device__ __forceinline__ void gates_B2(f2 (&loc)[32], const float* pp) {
  float s, c;  // RY wires 4..7 = bits 9..6
  sc(pp[4], s, c); ry_v<2>(loc, c, s);
  sc(pp[5], s, c); ry_v<1>(loc, c, s);
  sc(pp[6], s, c); ry_v<4>(loc, c, s);
  sc(pp[7], s, c); ry_v<3>(loc, c, s);
  cnot_v<2, 1>(loc);  // E(9,8)
  cnot_v<4, 3>(loc);  // E(7,6)
  cnot_v<1, 4>(loc);  // O(8,7)
  cnot_v<3, 0>(loc);  // O(6,5)
}

__device__ __forceinline__ void gates_Cm(f2 (&loc)[32], const float* p, int lA) {
  const float* pa = p + lA * 14; const float* pb = pa + 14;
  float s, c;
  if (lA > 0) {  // ABC-C RY wires 10..13 = bits 3..0
    sc(pa[10], s, c); ry_v<4>(loc, c, s);
    sc(pa[11], s, c); ry_v<3>(loc, c, s);
    sc(pa[12], s, c); ry_v<2>(loc, c, s);
    sc(pa[13], s, c); ry_v<1>(loc, c, s);
  }
  cnot_v<4, 3>(loc);  // E(3,2)
  cnot_v<2, 1>(loc);  // E(1,0)
  cnot_ic<4>(loc);    // O(4,3)
  cnot_v<3, 2>(loc);  // O(2,1)
  // CB'A-C of layer lA+1: RY wires 8..13 = bits 5..0
  sc(pb[8],  s, c); ry_v<0>(loc, c, s);
  sc(pb[9],  s, c); ry_intra(loc, c, s);
  sc(pb[10], s, c); ry_v<4>(loc, c, s);
  sc(pb[11], s, c); ry_v<3>(loc, c, s);
  sc(pb[12], s, c); ry_v<2>(loc, c, s);
  sc(pb[13], s, c); ry_v<1>(loc, c, s);
  cnot_ci<0>(loc);    // E(5,4)
  cnot_v<4, 3>(loc);  // E(3,2)
  cnot_v<2, 1>(loc);  // E(1,0)
  cnot_ic<4>(loc);    // O(4,3)
  cnot_v<3, 2>(loc);  // O(2,1)
}

__device__ __forceinline__ void gates_Am(f2 (&loc)[32], const float* p, int lA) {
  const float* pa = p + lA * 14; const float* pb = pa + 14;
  float s, c;  // CB'A-A of lA: RY wires 0..3 = bits 13..10
  sc(pa[0], s, c); ry_v<4>(loc, c, s);
  sc(pa[1], s, c); ry_v<3>(loc, c, s);
  sc(pa[2], s, c); ry_v<2>(loc, c, s);
  sc(pa[3], s, c); ry_v<1>(loc, c, s);
  cnot_v<4, 3>(loc);  // E(13,12)
  cnot_v<2, 1>(loc);  // E(11,10)
  cnot_v<3, 2>(loc);  // O(12,11)
  cnot_v<1, 0>(loc);  // O(10,9)
  // ABC-A of lA+1: RY wires 0..5 = bits 13..8
  sc(pb[0], s, c); ry_v<4>(loc, c, s);
  sc(pb[1], s, c); ry_v<3>(loc, c, s);
  sc(pb[2], s, c); ry_v<2>(loc, c, s);
  sc(pb[3], s, c); ry_v<1>(loc, c, s);
  sc(pb[4], s, c); ry_v<0>(loc, c, s);
  sc(pb[5], s, c); ry_intra(loc, c, s);
  cnot_v<4, 3>(loc);  // E(13,12)
  cnot_v<2, 1>(loc);  // E(11,10)
  cnot_ci<0>(loc);    // E(9,8)
  cnot_v<3, 2>(loc);  // O(12,11)
  cnot_v<1, 0>(loc);  // O(10,9)
}

__global__ __launch_bounds__(256) void vqc_kernel(const float* __restrict__ x,
                                                  const float* __restrict__ p,
                                                  float* __restrict__ out) {
  __shared__ float lds[16384];
  char* ldsb  = reinterpret_cast<char*>(lds);
  const int t = threadIdx.x;
  const int b = blockIdx.x;

  // Per-pass LDS byte bases (pure bit-permutation layouts; offsets are immediates)
  const int bA   = 16 * t;
  const int bC   = 16 * (t & 7) + 2048 * ((t >> 3) & 7) + 16384 * (t >> 6);
  const int bBab = 16 * (t & 3) + 64 * ((t >> 4) & 1) + 128 * ((t >> 6) & 1) +
                   4096 * ((t >> 2) & 3) + 16384 * ((t >> 5) & 1) + 32768 * ((t >> 7) & 1);
  const int bBbc = 16 * ((t >> 2) & 3) + 64 * ((t >> 5) & 1) + 128 * (t & 3) +
                   512 * ((t >> 4) & 1) + 1024 * ((t >> 6) & 1) + 32768 * ((t >> 7) & 1);

  f2 loc[32];

  // ================= P0: encoding + layer0 composed product + layer0 A-gates =================
  {
    float cw[NQ], sw[NQ];
#pragma unroll
    for (int q = 0; q < NQ; ++q) {
      float th = 0.5f * (x[b * NQ + q] + p[q]);
      sw[q] = __sinf(th);
      cw[q] = __cosf(th);
    }
    // wires 6..13 on thread bits: wire q <-> t bit (13-q)
    float P = 1.0f;
#pragma unroll
    for (int q = 6; q < NQ; ++q)
      P *= ((t >> (13 - q)) & 1) ? sw[q] : cw[q];
    // elem = wire5; v0..v4 = wires 4,3,2,1,0
    loc[0] = (f2){P * cw[5], P * sw[5]};
#pragma unroll
    for (int vb = 0; vb < 5; ++vb) {
      const int q = 4 - vb;
      const f2 cq = {cw[q], cw[q]}, sq = {sw[q], sw[q]};
#pragma unroll
      for (int m = 0; m < 32; ++m)
        if (m < (1 << vb)) {
          loc[m | (1 << vb)] = loc[m] * sq;
          loc[m]             = loc[m] * cq;
        }
    }
    cnot_v<4, 3>(loc);  // E(13,12)
    cnot_v<2, 1>(loc);  // E(11,10)
    cnot_ci<0>(loc);    // E(9,8)
    cnot_v<3, 2>(loc);  // O(12,11)
    cnot_v<1, 0>(loc);  // O(10,9)
    write_lin<4096>(loc, ldsb, bA);
    __syncthreads();
  }

  // ================= main merged-pass schedule =================
#pragma unroll 1
  for (int h = 0; h < 3; ++h) {
    const int lE = 2 * h;
    // B'1 pass (ABC layer lE)
    read_lin<256>(loc, ldsb, bBab);
    gates_B1(loc, p + lE * 14, h > 0);
    write_gather<8192, 16384, 2048, 4096>(loc, ldsb, bBbc);
    __syncthreads();
    // C merged pass (ABC layer lE + CB'A layer lE+1), in-place layout
    read_lin<128>(loc, ldsb, bC);
    gates_Cm(loc, p, lE);
    write_lin<128>(loc, ldsb, bC);
    __syncthreads();
    // B'2 pass (CB'A layer lE+1)
    read_b2(loc, ldsb, bBbc);
    gates_B2(loc, p + (lE + 1) * 14);
    write_gather<256, 512, 1024, 2048>(loc, ldsb, bBab);
    __syncthreads();
    // A merged pass (CB'A layer lE+1 + ABC layer lE+2), in-place layout
    if (h < 2) {
      read_lin<4096>(loc, ldsb, bA);
      gates_Am(loc, p, lE + 1);
      write_lin<4096>(loc, ldsb, bA);
      __syncthreads();
    }
  }

  // ================= P12: layer5 A-gates + measure <Z0> =================
  read_lin<4096>(loc, ldsb, bA);
  {
    const float* pp = p + 5 * 14;
    float s, c;
    sc(pp[0], s, c); ry_v<4>(loc, c, s);
    sc(pp[1], s, c); ry_v<3>(loc, c, s);
    sc(pp[2], s, c); ry_v<2>(loc, c, s);
    sc(pp[3], s, c); ry_v<1>(loc, c, s);
    cnot_v<4, 3>(loc);  // E(13,12)
    cnot_v<2, 1>(loc);  // E(11,10)
    cnot_v<3, 2>(loc);  // O(12,11)
    cnot_v<1, 0>(loc);  // O(10,9)
  }
  // bit13 (wire 0) = v4 = reg bit 4
  float acc = 0.f;
#pragma unroll
  for (int j = 0; j < 32; ++j) {
    float m = loc[j].x * loc[j].x + loc[j].y * loc[j].y;
    acc += (j & 16) ? -m : m;
  }
#pragma unroll
  for (int off = 32; off > 0; off >>= 1)
    acc += __shfl_down(acc, off, 64);
  __syncthreads();  // all state reads done; reuse LDS for partials
  if ((t & 63) == 0) lds[t >> 6] = acc;
  __syncthreads();
  if (t == 0) out[b] = lds[0] + lds[1] + lds[2] + lds[3];
}

extern "C" void kernel_launch(void* const* d_in, const int* in_sizes, int n_in,
                              void* d_out, int out_size, void* d_ws, size_t ws_size,
                              hipStream_t stream) {
  const float* x   = (const float*)d_in[0];   // (BATCH, 14) float32
  const float* prm = (const float*)d_in[1];   // (84,)      float32
  float* out       = (float*)d_out;           // (BATCH,)   float32
  const int batch  = in_sizes[0] / NQ;        // 128
  if (batch <= 0) return;
  vqc_kernel<<<dim3(batch), dim3(256), 0, stream>>>(x, prm, out);
}